// Round 1
// baseline (39266.348 us; speedup 1.0000x reference)
//
#include <hip/hip_runtime.h>
#include <hip/hip_cooperative_groups.h>

namespace cg = cooperative_groups;

#define TT 4096

// ws layout (float offsets):
//   M    @ 0        : 2048*64 = 131072   (W_in @ C)
//   wtil @ 131072   : 64                 (C^T @ dense_W[:64])
//   yp   @ 131200   : 4096*64 = 262144   (per-WG dense partials, [t][wg])
//   hb   @ 393344   : 2*2048             (h double buffer)
// total ~1.6 MB

__global__ void esn_prep(const float* __restrict__ C,
                         const float* __restrict__ Win,
                         const float* __restrict__ dW,
                         float* __restrict__ M,
                         float* __restrict__ wtil,
                         float* __restrict__ hb) {
  __shared__ float s[64];
  const int b = blockIdx.x, i = threadIdx.x;
  if (b < 2048) {
    s[i] = Win[b * 64 + i];
    __syncthreads();
    float acc = 0.f;
#pragma unroll 16
    for (int d = 0; d < 64; ++d) acc += s[d] * C[d * 64 + i];
    M[b * 64 + i] = acc;
  } else if (b == 2048) {
    s[i] = dW[i];
    __syncthreads();
    float acc = 0.f;
    for (int d = 0; d < 64; ++d) acc += s[d] * C[d * 64 + i];
    wtil[i] = acc;
  } else {
    // zero both h buffers (h_{-1} = 0)
    for (int k = i; k < 2 * 2048; k += 64) hb[k] = 0.f;
  }
}

// 64 WGs x 1024 threads. WG owns 32 rows; wave owns 2 rows; lane owns cols
// {4*lane + 256*k + j : k<8, j<4} of each row, weights held in registers.
__global__ __launch_bounds__(1024, 1) void esn_recur(
    const float* __restrict__ X, const float* __restrict__ M,
    const float* __restrict__ W, const float* __restrict__ dW,
    float* __restrict__ hb, float* __restrict__ yp) {
  cg::grid_group grid = cg::this_grid();
  __shared__ float sx[64];
  __shared__ float shh[2048];
  __shared__ float ps[16];
  const int tid = threadIdx.x;
  const int lane = tid & 63;
  const int wave = tid >> 6;
  const int row0 = (int)blockIdx.x * 32 + wave * 2;
  const float m0 = M[row0 * 64 + lane];
  const float m1 = M[(row0 + 1) * 64 + lane];
  const float dw0 = dW[64 + row0];
  const float dw1 = dW[64 + row0 + 1];
  // preload W_res rows into registers (survives any cache invalidation)
  const float* wp0 = W + (size_t)row0 * 2048 + (lane << 2);
  const float* wp1 = wp0 + 2048;
  float4 w0r[8], w1r[8];
#pragma unroll
  for (int k = 0; k < 8; ++k) {
    w0r[k] = *(const float4*)(wp0 + (k << 8));
    w1r[k] = *(const float4*)(wp1 + (k << 8));
  }
  for (int t = 0; t < TT; ++t) {
    const float* hprev = hb + (((t + 1) & 1) << 11);
    float* hnext = hb + ((t & 1) << 11);
    // stage h_{t-1} (2048 f) and x_t (64 f) into LDS
    if (tid < 512) {
      ((float4*)shh)[tid] = ((const float4*)hprev)[tid];
    } else if (tid < 528) {
      ((float4*)sx)[tid - 512] = ((const float4*)(X + t * 64))[tid - 512];
    }
    __syncthreads();
    float a0 = m0 * sx[lane];
    float a1 = m1 * sx[lane];
#pragma unroll
    for (int k = 0; k < 8; ++k) {
      const float4 h4 = *(const float4*)(shh + (k << 8) + (lane << 2));
      a0 += w0r[k].x * h4.x + w0r[k].y * h4.y + w0r[k].z * h4.z + w0r[k].w * h4.w;
      a1 += w1r[k].x * h4.x + w1r[k].y * h4.y + w1r[k].z * h4.z + w1r[k].w * h4.w;
    }
#pragma unroll
    for (int off = 32; off; off >>= 1) {
      a0 += __shfl_xor(a0, off, 64);
      a1 += __shfl_xor(a1, off, 64);
    }
    if (lane == 0) {
      const float h0 = tanhf(a0);
      const float h1 = tanhf(a1);
      hnext[row0] = h0;
      hnext[row0 + 1] = h1;
      ps[wave] = dw0 * h0 + dw1 * h1;
    }
    __syncthreads();
    if (tid == 0) {
      float s = 0.f;
#pragma unroll
      for (int wv = 0; wv < 16; ++wv) s += ps[wv];
      yp[t * 64 + blockIdx.x] = s;
    }
    grid.sync();
  }
}

__global__ void esn_out(const float* __restrict__ X,
                        const float* __restrict__ wtil,
                        const float* __restrict__ yp,
                        const float* __restrict__ bptr,
                        float* __restrict__ out) {
  const int tid = threadIdx.x;
  const int lane = tid & 63;
  const int wave = tid >> 6;
  const int t = blockIdx.x * 4 + wave;
  float v = wtil[lane] * X[t * 64 + lane] + yp[t * 64 + lane];
#pragma unroll
  for (int off = 32; off; off >>= 1) v += __shfl_xor(v, off, 64);
  if (lane == 0) out[t] = v + bptr[0];
}

extern "C" void kernel_launch(void* const* d_in, const int* in_sizes, int n_in,
                              void* d_out, int out_size, void* d_ws, size_t ws_size,
                              hipStream_t stream) {
  const float* X   = (const float*)d_in[0];
  const float* C   = (const float*)d_in[1];
  const float* Win = (const float*)d_in[2];
  const float* W   = (const float*)d_in[3];
  const float* dW  = (const float*)d_in[4];
  const float* db  = (const float*)d_in[5];
  float* ws   = (float*)d_ws;
  float* M    = ws;
  float* wtil = ws + 131072;
  float* yp   = ws + 131200;
  float* hb   = ws + 393344;

  esn_prep<<<2050, 64, 0, stream>>>(C, Win, dW, M, wtil, hb);

  void* args[] = {(void*)&X, (void*)&M, (void*)&W, (void*)&dW, (void*)&hb, (void*)&yp};
  hipLaunchCooperativeKernel(reinterpret_cast<void*>(&esn_recur), dim3(64),
                             dim3(1024), args, 0, stream);

  esn_out<<<1024, 256, 0, stream>>>(X, wtil, yp, db, (float*)d_out);
}

// Round 2
// 19135.435 us; speedup vs baseline: 2.0520x; 2.0520x over previous
//
#include <hip/hip_runtime.h>
#include <hip/hip_cooperative_groups.h>

#define TT 4096

typedef __attribute__((ext_vector_type(4))) float f4;

// ws layout (float offsets):
//   M     @ 0        : 2048*64 = 131072   (W_in @ C)
//   wtil  @ 131072   : 64                 (C^T @ dense_W[:64])
//   yp    @ 131200   : 4096*64 = 262144   (per-WG dense partials, [t][wg])
//   hb    @ 393344   : 2*2048             (h double buffer, L3-coherent traffic only)
//   flags @ 397440   : 64 uint            (per-WG step counters)

__global__ void esn_prep(const float* __restrict__ C,
                         const float* __restrict__ Win,
                         const float* __restrict__ dW,
                         float* __restrict__ M,
                         float* __restrict__ wtil,
                         float* __restrict__ hb,
                         unsigned int* __restrict__ flags) {
  __shared__ float s[64];
  const int b = blockIdx.x, i = threadIdx.x;
  if (b < 2048) {
    s[i] = Win[b * 64 + i];
    __syncthreads();
    float acc = 0.f;
#pragma unroll 16
    for (int d = 0; d < 64; ++d) acc += s[d] * C[d * 64 + i];
    M[b * 64 + i] = acc;
  } else if (b == 2048) {
    s[i] = dW[i];
    __syncthreads();
    float acc = 0.f;
    for (int d = 0; d < 64; ++d) acc += s[d] * C[d * 64 + i];
    wtil[i] = acc;
  } else {
    // zero both h buffers (h_{-1}=0) and the step flags
    for (int k = i; k < 2 * 2048; k += 64) hb[k] = 0.f;
    if (i < 64) flags[i] = 0u;
  }
}

// Coherent (cross-XCD) 16B load: bypasses L1/L2, served from Infinity Cache.
__device__ __forceinline__ f4 load_f4_coherent(const float* p) {
  f4 v;
  asm volatile("global_load_dwordx4 %0, %1, off sc0 sc1\n\t"
               "s_waitcnt vmcnt(0)"
               : "=&v"(v) : "v"(p) : "memory");
  return v;
}

// 64 WGs x 1024 threads. WG owns 32 rows; wave owns 2 rows; lane owns cols
// {4*lane + 256*k + j : k<8, j<4}; weights held in registers (no call in loop).
__global__ __launch_bounds__(1024, 4) void esn_recur(
    const float* __restrict__ X, const float* __restrict__ M,
    const float* __restrict__ W, const float* __restrict__ dW,
    float* __restrict__ hb, float* __restrict__ yp,
    unsigned int* __restrict__ flags) {
  __shared__ float sx[64];
  __shared__ float shh[2048];
  __shared__ float ps[16];
  const int tid = threadIdx.x;
  const int lane = tid & 63;
  const int wave = tid >> 6;
  const int row0 = (int)blockIdx.x * 32 + wave * 2;
  const float m0 = M[row0 * 64 + lane];
  const float m1 = M[(row0 + 1) * 64 + lane];
  const float dw0 = dW[64 + row0];
  const float dw1 = dW[64 + row0 + 1];
  const float* wp0 = W + (size_t)row0 * 2048 + (lane << 2);
  const float* wp1 = wp0 + 2048;
  f4 w0r[8], w1r[8];
#pragma unroll
  for (int k = 0; k < 8; ++k) {
    w0r[k] = *(const f4*)(wp0 + (k << 8));
    w1r[k] = *(const f4*)(wp1 + (k << 8));
  }
  for (int t = 0; t < TT; ++t) {
    // ---- wait until every WG has published step t-1 ----
    if (t > 0 && tid < 64) {
      while (__hip_atomic_load(&flags[tid], __ATOMIC_RELAXED,
                               __HIP_MEMORY_SCOPE_AGENT) < (unsigned)t) {
      }
    }
    __syncthreads();
    // ---- stage h_{t-1} (slot (t-1)&1, coherent loads) and x_t into LDS ----
    const float* hprev = hb + (((t + 1) & 1) << 11);
    float* hnext = hb + ((t & 1) << 11);
    if (tid < 512) {
      ((f4*)shh)[tid] = load_f4_coherent(hprev + (tid << 2));
    } else if (tid < 528) {
      ((float4*)sx)[tid - 512] = ((const float4*)(X + t * 64))[tid - 512];
    }
    __syncthreads();
    // ---- 2 rows per wave: dot(W_res_row, h) + dot(M_row, x) ----
    float a0 = m0 * sx[lane];
    float a1 = m1 * sx[lane];
#pragma unroll
    for (int k = 0; k < 8; ++k) {
      const f4 h4 = *(const f4*)(shh + (k << 8) + (lane << 2));
      a0 += w0r[k].x * h4.x + w0r[k].y * h4.y + w0r[k].z * h4.z + w0r[k].w * h4.w;
      a1 += w1r[k].x * h4.x + w1r[k].y * h4.y + w1r[k].z * h4.z + w1r[k].w * h4.w;
    }
#pragma unroll
    for (int off = 32; off; off >>= 1) {
      a0 += __shfl_xor(a0, off, 64);
      a1 += __shfl_xor(a1, off, 64);
    }
    if (lane == 0) {
      const float h0 = tanhf(a0);
      const float h1 = tanhf(a1);
      // write-through to the coherence point (L3)
      __hip_atomic_store(&hnext[row0], h0, __ATOMIC_RELAXED, __HIP_MEMORY_SCOPE_AGENT);
      __hip_atomic_store(&hnext[row0 + 1], h1, __ATOMIC_RELAXED, __HIP_MEMORY_SCOPE_AGENT);
      ps[wave] = dw0 * h0 + dw1 * h1;
    }
    // barrier drains vmcnt -> all 32 h stores are at L3 before flag publish
    __syncthreads();
    if (tid == 0) {
      __hip_atomic_store(&flags[blockIdx.x], (unsigned)(t + 1),
                         __ATOMIC_RELEASE, __HIP_MEMORY_SCOPE_AGENT);
      // epilogue off the inter-WG critical path
      float s = 0.f;
#pragma unroll
      for (int wv = 0; wv < 16; ++wv) s += ps[wv];
      yp[t * 64 + blockIdx.x] = s;
    }
  }
}

__global__ void esn_out(const float* __restrict__ X,
                        const float* __restrict__ wtil,
                        const float* __restrict__ yp,
                        const float* __restrict__ bptr,
                        float* __restrict__ out) {
  const int tid = threadIdx.x;
  const int lane = tid & 63;
  const int wave = tid >> 6;
  const int t = blockIdx.x * 4 + wave;
  float v = wtil[lane] * X[t * 64 + lane] + yp[t * 64 + lane];
#pragma unroll
  for (int off = 32; off; off >>= 1) v += __shfl_xor(v, off, 64);
  if (lane == 0) out[t] = v + bptr[0];
}

extern "C" void kernel_launch(void* const* d_in, const int* in_sizes, int n_in,
                              void* d_out, int out_size, void* d_ws, size_t ws_size,
                              hipStream_t stream) {
  const float* X   = (const float*)d_in[0];
  const float* C   = (const float*)d_in[1];
  const float* Win = (const float*)d_in[2];
  const float* W   = (const float*)d_in[3];
  const float* dW  = (const float*)d_in[4];
  const float* db  = (const float*)d_in[5];
  float* ws   = (float*)d_ws;
  float* M    = ws;
  float* wtil = ws + 131072;
  float* yp   = ws + 131200;
  float* hb   = ws + 393344;
  unsigned int* flags = (unsigned int*)(ws + 397440);

  esn_prep<<<2050, 64, 0, stream>>>(C, Win, dW, M, wtil, hb, flags);

  void* args[] = {(void*)&X, (void*)&M, (void*)&W, (void*)&dW,
                  (void*)&hb, (void*)&yp, (void*)&flags};
  hipLaunchCooperativeKernel(reinterpret_cast<void*>(&esn_recur), dim3(64),
                             dim3(1024), args, 0, stream);

  esn_out<<<1024, 256, 0, stream>>>(X, wtil, yp, db, (float*)d_out);
}

// Round 3
// 14222.971 us; speedup vs baseline: 2.7608x; 1.3454x over previous
//
#include <hip/hip_runtime.h>
#include <hip/hip_cooperative_groups.h>

#define TT 4096

typedef __attribute__((ext_vector_type(4))) float f4;
typedef __attribute__((ext_vector_type(2))) unsigned int u2;

// ws layout (float offsets):
//   M     @ 0        : 2048*64 = 131072   (W_in @ C)
//   wtil  @ 131072   : 64                 (C^T @ dense_W[:64])
//   yp    @ 131200   : 4096*128 = 524288  (per-WG dense partials, [t][wg])
//   pairs @ 655488   : 2 slots * 2048 * (u32 tag, f32 h) = 8192 floats
// total ~2.65 MB

__global__ void esn_prep(const float* __restrict__ C,
                         const float* __restrict__ Win,
                         const float* __restrict__ dW,
                         float* __restrict__ M,
                         float* __restrict__ wtil,
                         u2* __restrict__ pairs) {
  __shared__ float s[64];
  const int b = blockIdx.x, i = threadIdx.x;
  if (b < 2048) {
    s[i] = Win[b * 64 + i];
    __syncthreads();
    float acc = 0.f;
#pragma unroll 16
    for (int d = 0; d < 64; ++d) acc += s[d] * C[d * 64 + i];
    M[b * 64 + i] = acc;
  } else if (b == 2048) {
    s[i] = dW[i];
    __syncthreads();
    float acc = 0.f;
    for (int d = 0; d < 64; ++d) acc += s[d] * C[d * 64 + i];
    wtil[i] = acc;
  } else {
    // zero both pair slots: tag=0 matches step 0's expectation, h=0
    u2 z; z.x = 0u; z.y = 0u;
    for (int k = i; k < 2 * 2048; k += 64) pairs[k] = z;
  }
}

// 128 WGs x 1024 threads. WG owns 16 rows; each wave owns 1 row; lane owns
// cols {4*lane + 256*k : k<8} (8 f4 = 32 weight VGPRs, register-resident).
// h published as (tag,h) 8-B pairs -> single L3 round trip per step.
__global__ __launch_bounds__(1024, 4) void esn_recur(
    const float* __restrict__ X, const float* __restrict__ M,
    const float* __restrict__ W, const float* __restrict__ dW,
    u2* __restrict__ pairs, float* __restrict__ yp) {
  __shared__ float shh[2048];
  __shared__ float ps[16];
  const int tid = threadIdx.x;
  const int lane = tid & 63;
  const int wave = tid >> 6;
  const int row = (int)blockIdx.x * 16 + wave;
  const float m = M[row * 64 + lane];
  const float dwv = dW[64 + row];
  const float* wp = W + (size_t)row * 2048 + (lane << 2);
  f4 wr[8];
#pragma unroll
  for (int k = 0; k < 8; ++k) wr[k] = *(const f4*)(wp + (k << 8));

  for (int t = 0; t < TT; ++t) {
    // prefetch x_t (read-only, L1-broadcast across waves)
    const float xv = X[t * 64 + lane];
    // ---- spin until both owned pairs of slot (t-1)&1 carry tag t ----
    const unsigned tg = (unsigned)t;
    const u2* base = pairs + (((t + 1) & 1) << 11);
    const u2* a0 = base + tid;
    const u2* a1 = base + tid + 1024;
    u2 p0, p1;
    for (;;) {
      asm volatile(
          "global_load_dwordx2 %0, %2, off sc0 sc1\n\t"
          "global_load_dwordx2 %1, %3, off sc0 sc1\n\t"
          "s_waitcnt vmcnt(0)"
          : "=&v"(p0), "=&v"(p1)
          : "v"(a0), "v"(a1)
          : "memory");
      if (p0.x == tg && p1.x == tg) break;
      __builtin_amdgcn_s_sleep(1);
    }
    shh[tid] = __uint_as_float(p0.y);
    shh[tid + 1024] = __uint_as_float(p1.y);
    __syncthreads();
    // ---- one row per wave: dot(W_row, h) + dot(M_row, x) ----
    float a = m * xv;
#pragma unroll
    for (int k = 0; k < 8; ++k) {
      const f4 h4 = *(const f4*)(shh + (k << 8) + (lane << 2));
      a += wr[k].x * h4.x + wr[k].y * h4.y + wr[k].z * h4.z + wr[k].w * h4.w;
    }
#pragma unroll
    for (int off = 32; off; off >>= 1) a += __shfl_xor(a, off, 64);
    if (lane == 0) {
      const float h = tanhf(a);
      u2 pv;
      pv.x = tg + 1u;
      pv.y = __float_as_uint(h);
      u2* dst = pairs + ((t & 1) << 11) + row;
      asm volatile("global_store_dwordx2 %0, %1, off sc0 sc1"
                   :: "v"(dst), "v"(pv) : "memory");
      ps[wave] = dwv * h;
    }
    __syncthreads();
    if (tid == 0) {
      float s = 0.f;
#pragma unroll
      for (int wv = 0; wv < 16; ++wv) s += ps[wv];
      yp[t * 128 + blockIdx.x] = s;
    }
  }
}

__global__ void esn_out(const float* __restrict__ X,
                        const float* __restrict__ wtil,
                        const float* __restrict__ yp,
                        const float* __restrict__ bptr,
                        float* __restrict__ out) {
  const int tid = threadIdx.x;
  const int lane = tid & 63;
  const int wave = tid >> 6;
  const int t = blockIdx.x * 4 + wave;
  float v = wtil[lane] * X[t * 64 + lane] + yp[t * 128 + lane] + yp[t * 128 + 64 + lane];
#pragma unroll
  for (int off = 32; off; off >>= 1) v += __shfl_xor(v, off, 64);
  if (lane == 0) out[t] = v + bptr[0];
}

extern "C" void kernel_launch(void* const* d_in, const int* in_sizes, int n_in,
                              void* d_out, int out_size, void* d_ws, size_t ws_size,
                              hipStream_t stream) {
  const float* X   = (const float*)d_in[0];
  const float* C   = (const float*)d_in[1];
  const float* Win = (const float*)d_in[2];
  const float* W   = (const float*)d_in[3];
  const float* dW  = (const float*)d_in[4];
  const float* db  = (const float*)d_in[5];
  float* ws   = (float*)d_ws;
  float* M    = ws;
  float* wtil = ws + 131072;
  float* yp   = ws + 131200;
  u2*    pairs = (u2*)(ws + 655488);

  esn_prep<<<2050, 64, 0, stream>>>(C, Win, dW, M, wtil, pairs);

  void* args[] = {(void*)&X, (void*)&M, (void*)&W, (void*)&dW,
                  (void*)&pairs, (void*)&yp};
  hipLaunchCooperativeKernel(reinterpret_cast<void*>(&esn_recur), dim3(128),
                             dim3(1024), args, 0, stream);

  esn_out<<<1024, 256, 0, stream>>>(X, wtil, yp, db, (float*)d_out);
}